// Round 9
// baseline (187.531 us; speedup 1.0000x reference)
//
#include <hip/hip_runtime.h>

// IDCST2 via FFTs: out = C0 @ (x @ S1^T), M=N=4096, fp32.
//   DST-III rows:  s_v = (-1)^v * DCT3(reverse(x))_v  (c_0 = 0)
//   DCT-III via N-pt complex DFT (inverse Makhoul):
//     W_k = (c_k - i c_{N-k}) e^{i pi k/2N};  v = DFT_+(W)
//     y_{2n} = (Re v_n + c_0)/2 ; y_{2n+1} = (Re v_{N-1-n} + c_0)/2
//   v real => pack 2 rows per complex FFT (Re/Im). 1/2 folded into pack.
// FFT: radix-16 register FFT, 4096 = 16^3. Pass A entirely in registers
//   (pack fragment set == pass-A fragment set, same thread), then 2 LDS
//   exchanges (XOR-swizzled, conflict-free), 5 barriers, 32 KiB LDS.
// [r9 isolation step: r4-verified source + STAGED PACK LOADS ONLY.
//  r5's other edits (dropped pass-B barrier, launch_bounds(256,5)) stay
//  backed out — r5's binary killed containers 3x; isolating one variable.]
// Pipeline (ALL global access fully coalesced; r3 showed scattered 16B/8B
// stores cost ~3x partial-line writeback amplification => avoid):
//   dst_rows(x->ws) ; T(ws->out) ; dct_rows(out->ws) ; T(ws->out).

#define NF 4096
#define TWOPI_16384 3.8349519697141029e-4f  // 2*pi/16384
#define TWOPI_4096  1.5339807878856412e-3f  // 2*pi/4096
#define TWOPI_256   2.4543692606170259e-2f  // 2*pi/256

__device__ __forceinline__ float2 cmul(float2 a, float2 b) {
    return make_float2(a.x * b.x - a.y * b.y, a.x * b.y + a.y * b.x);
}
__device__ __forceinline__ float2 cadd(float2 a, float2 b) {
    return make_float2(a.x + b.x, a.y + b.y);
}
__device__ __forceinline__ float2 csub(float2 a, float2 b) {
    return make_float2(a.x - b.x, a.y - b.y);
}
__device__ __forceinline__ float2 muli(float2 a) {  // +i * a (positive-sign DFT)
    return make_float2(-a.y, a.x);
}

// 16-point DFT_+ in registers, natural order in/out (verified r2/r3).
__device__ __forceinline__ void fft16(float2 f[16]) {
    float2 s[16];
#pragma unroll
    for (int b = 0; b < 4; ++b) {
        float2 x0 = f[b], x1 = f[b + 4], x2 = f[b + 8], x3 = f[b + 12];
        float2 t0 = cadd(x0, x2), t1 = csub(x0, x2);
        float2 t2 = cadd(x1, x3), t3 = csub(x1, x3);
        s[b]      = cadd(t0, t2);
        s[4 + b]  = cadd(t1, muli(t3));
        s[8 + b]  = csub(t0, t2);
        s[12 + b] = csub(t1, muli(t3));
    }
    const float2 w1 = make_float2(0.92387953251128674f, 0.38268343236508977f);
    const float2 w2 = make_float2(0.70710678118654752f, 0.70710678118654752f);
    const float2 w3 = make_float2(0.38268343236508977f, 0.92387953251128674f);
    const float2 w6 = make_float2(-0.70710678118654752f, 0.70710678118654752f);
    const float2 w9 = make_float2(-0.92387953251128674f, -0.38268343236508977f);
    s[5]  = cmul(s[5], w1);
    s[6]  = cmul(s[6], w2);
    s[7]  = cmul(s[7], w3);
    s[9]  = cmul(s[9], w2);
    s[10] = muli(s[10]);
    s[11] = cmul(s[11], w6);
    s[13] = cmul(s[13], w3);
    s[14] = cmul(s[14], w6);
    s[15] = cmul(s[15], w9);
#pragma unroll
    for (int al = 0; al < 4; ++al) {
        float2 x0 = s[4 * al + 0], x1 = s[4 * al + 1];
        float2 x2 = s[4 * al + 2], x3 = s[4 * al + 3];
        float2 t0 = cadd(x0, x2), t1 = csub(x0, x2);
        float2 t2 = cadd(x1, x3), t3 = csub(x1, x3);
        f[al]      = cadd(t0, t2);
        f[4 + al]  = cadd(t1, muli(t3));
        f[8 + al]  = csub(t0, t2);
        f[12 + al] = csub(t1, muli(t3));
    }
}

// Pass A tail: r[] holds W_{i*256+t}; fft16, twiddle E(t*k1/4096), store.
__device__ __forceinline__ void fftA_store(float2 r[16], float2* __restrict__ buf,
                                           const int t) {
    fft16(r);
    float sn, cs;
    __sincosf((float)t * TWOPI_4096, &sn, &cs);
    const float2 wb = make_float2(cs, sn);
    float2 w = wb;
#pragma unroll
    for (int k1 = 1; k1 < 16; ++k1) { r[k1] = cmul(r[k1], w); w = cmul(w, wb); }
#pragma unroll
    for (int i = 0; i < 16; ++i) buf[i * 256 + t] = r[i];
}

// Passes B and C (A-output already in buf). Leaves X natural order.
// XOR-swizzled middle exchange: D[k1,j1,m2] at k1*256 + j1*16 + (m2^k1).
__device__ __forceinline__ void fft4096_tail(float2* __restrict__ buf, const int t) {
    float2 r[16];
    __syncthreads();  // (1) A writes -> B reads
    {
        const int k1 = t >> 4, m2 = t & 15;
        const int base = k1 * 256 + m2;
#pragma unroll
        for (int i = 0; i < 16; ++i) r[i] = buf[base + i * 16];
        fft16(r);
        float sn, cs;
        __sincosf((float)m2 * TWOPI_256, &sn, &cs);
        const float2 wb = make_float2(cs, sn);
        float2 w = wb;
#pragma unroll
        for (int j1 = 1; j1 < 16; ++j1) { r[j1] = cmul(r[j1], w); w = cmul(w, wb); }
        __syncthreads();  // (2) B reads -> B swizzled writes
        const int bw = k1 * 256 + (m2 ^ k1);
#pragma unroll
        for (int j1 = 0; j1 < 16; ++j1) buf[bw + j1 * 16] = r[j1];
    }
    __syncthreads();  // (3) B writes -> C reads
    {
        const int k1 = t & 15;
        const int bc = k1 * 256 + (t >> 4) * 16;
#pragma unroll
        for (int i = 0; i < 16; ++i) r[i] = buf[bc + (i ^ k1)];
        fft16(r);
        __syncthreads();  // (4) C reads -> natural-order writes
#pragma unroll
        for (int j2 = 0; j2 < 16; ++j2) buf[j2 * 256 + t] = r[j2];
    }
    __syncthreads();  // (5) C writes -> unpack reads
}

// ---- stage 1: DST-III along rows; two rows per block ----
__global__ __launch_bounds__(256) void dst_rows_k(const float* __restrict__ x,
                                                  float* __restrict__ y) {
    __shared__ float2 buf[4096];  // 32 KiB
    const int t = threadIdx.x;
    const size_t r0 = (size_t)blockIdx.x * 2;
    const float* x0 = x + r0 * NF;
    const float* x1 = x0 + NF;

    // pack directly into pass-A fragments r[i] = W_{i*256+t}:
    // W_k = [(x0[N-k]+x1[k]) + i(x1[N-k]-x0[k])] * 0.5*e^{i pi k/8192}, W_0=0
    // loads staged in 8-iter chunks (32 in flight) for latency hiding
    float sn, cs;
    __sincosf((float)t * TWOPI_16384, &sn, &cs);
    float2 w = make_float2(0.5f * cs, 0.5f * sn);  // 1/2 folded in
    const float2 stp = make_float2(0.99518472667219693f, 0.09801714032956060f);
    float2 r[16];
#pragma unroll
    for (int h = 0; h < 2; ++h) {
        float a8[8], b8[8], c8[8], d8[8];
#pragma unroll
        for (int j = 0; j < 8; ++j) {
            const int k = t + 256 * (8 * h + j);
            const int kc = k ? k : 1;
            a8[j] = x0[NF - kc];
            b8[j] = x1[kc];
            c8[j] = x1[NF - kc];
            d8[j] = x0[kc];
        }
#pragma unroll
        for (int j = 0; j < 8; ++j) {
            const int i = 8 * h + j;
            const int k = t + 256 * i;
            float2 ww = make_float2(0.f, 0.f);
            if (k > 0) {
                float re = a8[j] + b8[j];
                float im = c8[j] - d8[j];
                ww = make_float2(re * w.x - im * w.y, re * w.y + im * w.x);
            }
            r[i] = ww;
            w = cmul(w, stp);
        }
    }
    fftA_store(r, buf, t);
    fft4096_tail(buf, t);

    // unpack with DST sign (scale folded): y[2n] = Re v_n, y[2n+1] = -Re v_{N-1-n}
    float* y0 = y + r0 * NF;
    float* y1 = y0 + NF;
#pragma unroll
    for (int u = 0; u < 8; ++u) {
        const int n = t + 256 * u;
        float2 vn = buf[n];
        float2 vm = buf[NF - 1 - n];
        ((float2*)y0)[n] = make_float2(vn.x, -vm.x);
        ((float2*)y1)[n] = make_float2(vn.y, -vm.y);
    }
}

// ---- stage 2: DCT-III along rows of yT; two rows per block ----
__global__ __launch_bounds__(256) void dct_rows_k(const float* __restrict__ yt,
                                                  float* __restrict__ ot) {
    __shared__ float2 buf[4096];
    const int t = threadIdx.x;
    const size_t r0 = (size_t)blockIdx.x * 2;
    const float* t0 = yt + r0 * NF;
    const float* t1 = t0 + NF;
    const float a0h = 0.5f * t0[0];
    const float a1h = 0.5f * t1[0];

    // pack (c_N := 0): k=0: W_0 = 0.5*(c0 + i c'0)
    // k>0: W_k = [(t0[k]+t1[N-k]) + i(t1[k]-t0[N-k])] * 0.5*e^{i pi k/8192}
    float sn, cs;
    __sincosf((float)t * TWOPI_16384, &sn, &cs);
    float2 w = make_float2(0.5f * cs, 0.5f * sn);
    const float2 stp = make_float2(0.99518472667219693f, 0.09801714032956060f);
    float2 r[16];
#pragma unroll
    for (int h = 0; h < 2; ++h) {
        float a8[8], b8[8], c8[8], d8[8];
#pragma unroll
        for (int j = 0; j < 8; ++j) {
            const int k = t + 256 * (8 * h + j);
            const int kc = k ? k : 1;
            a8[j] = t0[kc];
            b8[j] = t1[NF - kc];
            c8[j] = t1[kc];
            d8[j] = t0[NF - kc];
        }
#pragma unroll
        for (int j = 0; j < 8; ++j) {
            const int i = 8 * h + j;
            const int k = t + 256 * i;
            float2 ww;
            if (k == 0) {
                ww = make_float2(a0h, a1h);
            } else {
                float re = a8[j] + b8[j];
                float im = c8[j] - d8[j];
                ww = make_float2(re * w.x - im * w.y, re * w.y + im * w.x);
            }
            r[i] = ww;
            w = cmul(w, stp);
        }
    }
    fftA_store(r, buf, t);
    fft4096_tail(buf, t);

    // unpack (scale folded): o[2n] = Re v_n + a0h, o[2n+1] = Re v_{N-1-n} + a0h
    float* o0 = ot + r0 * NF;
    float* o1 = o0 + NF;
#pragma unroll
    for (int u = 0; u < 8; ++u) {
        const int n = t + 256 * u;
        float2 vn = buf[n];
        float2 vm = buf[NF - 1 - n];
        ((float2*)o0)[n] = make_float2(vn.x + a0h, vm.x + a0h);
        ((float2*)o1)[n] = make_float2(vn.y + a1h, vm.y + a1h);
    }
}

// ---- 32x32 LDS-tiled transpose, float4 IO: out[c][r] = in[r][c] ----
__global__ __launch_bounds__(256) void transpose_k(const float* __restrict__ in,
                                                   float* __restrict__ out) {
    __shared__ float tile[32][33];
    const int tx = threadIdx.x;  // 0..7
    const int ty = threadIdx.y;  // 0..31
    const int c0 = blockIdx.x * 32;
    const int r0 = blockIdx.y * 32;

    float4 v = *(const float4*)(in + (size_t)(r0 + ty) * NF + c0 + 4 * tx);
    tile[ty][4 * tx + 0] = v.x;
    tile[ty][4 * tx + 1] = v.y;
    tile[ty][4 * tx + 2] = v.z;
    tile[ty][4 * tx + 3] = v.w;
    __syncthreads();

    float4 o;
    o.x = tile[4 * tx + 0][ty];
    o.y = tile[4 * tx + 1][ty];
    o.z = tile[4 * tx + 2][ty];
    o.w = tile[4 * tx + 3][ty];
    *(float4*)(out + (size_t)(c0 + ty) * NF + r0 + 4 * tx) = o;
}

extern "C" void kernel_launch(void* const* d_in, const int* in_sizes, int n_in,
                              void* d_out, int out_size, void* d_ws, size_t ws_size,
                              hipStream_t stream) {
    const float* x = (const float*)d_in[0];
    float* out = (float*)d_out;
    float* y = (float*)d_ws;  // 64 MiB scratch

    dim3 tgrid(128, 128), tblk(8, 32);

    // y[p,v] = DST3 rows of x
    dst_rows_k<<<2048, 256, 0, stream>>>(x, y);
    // out = yT
    transpose_k<<<tgrid, tblk, 0, stream>>>(y, out);
    // y[v,u] = DCT3 rows of yT  (= out[u,v] transposed)
    dct_rows_k<<<2048, 256, 0, stream>>>(out, y);
    // out[u,v]
    transpose_k<<<tgrid, tblk, 0, stream>>>(y, out);
}

// Round 11
// 179.897 us; speedup vs baseline: 1.0424x; 1.0424x over previous
//
#include <hip/hip_runtime.h>

// IDCST2 via FFTs: out = C0 @ (x @ S1^T), M=N=4096, fp32.
// Stage 1 (rows): y[p][v] = DST3(x[p])[v]  -- verified dst_rows_k (r4).
// Stage 2 (cols): out[:,v] = DCT3(y[:,v]) via Makhoul pack + 4096-pt DFT_+,
//   SPLIT 16x256 over the row index p (k = j*256 + s) so NO transposes:
//   K2a: G_a[s] = FFT16_j W_{j*256+s};  H_a[s] = G_a[s]*E(a s/4096)
//   K2b: v_{a+16m} = DFT256_s H_a[s]  (two FFT16 passes + LDS exchange),
//        unpack n' in [0,2048): rows 2n' from v_{n'}, 2n'+1 from v_{4095-n'};
//        n' = na + 16m (m<128), partner = (15-na, 255-m) inside the block.
//        [r10 bug: m ran 0..255 -> out rows up to 8191 = OOB. Fixed.]
// Pipeline: dst_rows(x->y) ; colpass1(y->H) ; colpass2(H->out).
// Fallback: if ws_size < 128 MiB, run the verified 4-kernel path.

#define NF 4096
#define TWOPI_16384 3.8349519697141029e-4f  // 2*pi/16384
#define TWOPI_4096  1.5339807878856412e-3f  // 2*pi/4096
#define TWOPI_256   2.4543692606170259e-2f  // 2*pi/256

__device__ __forceinline__ float2 cmul(float2 a, float2 b) {
    return make_float2(a.x * b.x - a.y * b.y, a.x * b.y + a.y * b.x);
}
__device__ __forceinline__ float2 cadd(float2 a, float2 b) {
    return make_float2(a.x + b.x, a.y + b.y);
}
__device__ __forceinline__ float2 csub(float2 a, float2 b) {
    return make_float2(a.x - b.x, a.y - b.y);
}
__device__ __forceinline__ float2 muli(float2 a) {  // +i * a (positive-sign DFT)
    return make_float2(-a.y, a.x);
}

// 16-point DFT_+ in registers, natural order in/out (verified r2/r3).
__device__ __forceinline__ void fft16(float2 f[16]) {
    float2 s[16];
#pragma unroll
    for (int b = 0; b < 4; ++b) {
        float2 x0 = f[b], x1 = f[b + 4], x2 = f[b + 8], x3 = f[b + 12];
        float2 t0 = cadd(x0, x2), t1 = csub(x0, x2);
        float2 t2 = cadd(x1, x3), t3 = csub(x1, x3);
        s[b]      = cadd(t0, t2);
        s[4 + b]  = cadd(t1, muli(t3));
        s[8 + b]  = csub(t0, t2);
        s[12 + b] = csub(t1, muli(t3));
    }
    const float2 w1 = make_float2(0.92387953251128674f, 0.38268343236508977f);
    const float2 w2 = make_float2(0.70710678118654752f, 0.70710678118654752f);
    const float2 w3 = make_float2(0.38268343236508977f, 0.92387953251128674f);
    const float2 w6 = make_float2(-0.70710678118654752f, 0.70710678118654752f);
    const float2 w9 = make_float2(-0.92387953251128674f, -0.38268343236508977f);
    s[5]  = cmul(s[5], w1);
    s[6]  = cmul(s[6], w2);
    s[7]  = cmul(s[7], w3);
    s[9]  = cmul(s[9], w2);
    s[10] = muli(s[10]);
    s[11] = cmul(s[11], w6);
    s[13] = cmul(s[13], w3);
    s[14] = cmul(s[14], w6);
    s[15] = cmul(s[15], w9);
#pragma unroll
    for (int al = 0; al < 4; ++al) {
        float2 x0 = s[4 * al + 0], x1 = s[4 * al + 1];
        float2 x2 = s[4 * al + 2], x3 = s[4 * al + 3];
        float2 t0 = cadd(x0, x2), t1 = csub(x0, x2);
        float2 t2 = cadd(x1, x3), t3 = csub(x1, x3);
        f[al]      = cadd(t0, t2);
        f[4 + al]  = cadd(t1, muli(t3));
        f[8 + al]  = csub(t0, t2);
        f[12 + al] = csub(t1, muli(t3));
    }
}

// Pass A tail: r[] holds W_{i*256+t}; fft16, twiddle E(t*k1/4096), store.
__device__ __forceinline__ void fftA_store(float2 r[16], float2* __restrict__ buf,
                                           const int t) {
    fft16(r);
    float sn, cs;
    __sincosf((float)t * TWOPI_4096, &sn, &cs);
    const float2 wb = make_float2(cs, sn);
    float2 w = wb;
#pragma unroll
    for (int k1 = 1; k1 < 16; ++k1) { r[k1] = cmul(r[k1], w); w = cmul(w, wb); }
#pragma unroll
    for (int i = 0; i < 16; ++i) buf[i * 256 + t] = r[i];
}

// Passes B and C (A-output already in buf). Leaves X natural order.
__device__ __forceinline__ void fft4096_tail(float2* __restrict__ buf, const int t) {
    float2 r[16];
    __syncthreads();  // (1) A writes -> B reads
    {
        const int k1 = t >> 4, m2 = t & 15;
        const int base = k1 * 256 + m2;
#pragma unroll
        for (int i = 0; i < 16; ++i) r[i] = buf[base + i * 16];
        fft16(r);
        float sn, cs;
        __sincosf((float)m2 * TWOPI_256, &sn, &cs);
        const float2 wb = make_float2(cs, sn);
        float2 w = wb;
#pragma unroll
        for (int j1 = 1; j1 < 16; ++j1) { r[j1] = cmul(r[j1], w); w = cmul(w, wb); }
        __syncthreads();  // (2) B reads -> B swizzled writes
        const int bw = k1 * 256 + (m2 ^ k1);
#pragma unroll
        for (int j1 = 0; j1 < 16; ++j1) buf[bw + j1 * 16] = r[j1];
    }
    __syncthreads();  // (3) B writes -> C reads
    {
        const int k1 = t & 15;
        const int bc = k1 * 256 + (t >> 4) * 16;
#pragma unroll
        for (int i = 0; i < 16; ++i) r[i] = buf[bc + (i ^ k1)];
        fft16(r);
        __syncthreads();  // (4) C reads -> natural-order writes
#pragma unroll
        for (int j2 = 0; j2 < 16; ++j2) buf[j2 * 256 + t] = r[j2];
    }
    __syncthreads();  // (5) C writes -> unpack reads
}

// ---- stage 1: DST-III along rows; two rows per block (verified r4) ----
__global__ __launch_bounds__(256) void dst_rows_k(const float* __restrict__ x,
                                                  float* __restrict__ y) {
    __shared__ float2 buf[4096];  // 32 KiB
    const int t = threadIdx.x;
    const size_t r0 = (size_t)blockIdx.x * 2;
    const float* x0 = x + r0 * NF;
    const float* x1 = x0 + NF;

    float sn, cs;
    __sincosf((float)t * TWOPI_16384, &sn, &cs);
    float2 w = make_float2(0.5f * cs, 0.5f * sn);  // 1/2 folded in
    const float2 stp = make_float2(0.99518472667219693f, 0.09801714032956060f);
    float2 r[16];
#pragma unroll
    for (int i = 0; i < 16; ++i) {
        const int k = t + 256 * i;
        float2 ww = make_float2(0.f, 0.f);
        if (k > 0) {
            float re = x0[NF - k] + x1[k];
            float im = x1[NF - k] - x0[k];
            ww = make_float2(re * w.x - im * w.y, re * w.y + im * w.x);
        }
        r[i] = ww;
        w = cmul(w, stp);
    }
    fftA_store(r, buf, t);
    fft4096_tail(buf, t);

    float* y0 = y + r0 * NF;
    float* y1 = y0 + NF;
#pragma unroll
    for (int u = 0; u < 8; ++u) {
        const int n = t + 256 * u;
        float2 vn = buf[n];
        float2 vm = buf[NF - 1 - n];
        ((float2*)y0)[n] = make_float2(vn.x, -vm.x);
        ((float2*)y1)[n] = make_float2(vn.y, -vm.y);
    }
}

// ---- K2a: column pack + FFT16 over j + twiddle -> H  (no LDS) ----
// H[a*256+s][cpair] = E(a s/4096) * sum_j W_{j*256+s} E(a j/16)
__global__ __launch_bounds__(256) void colpass1_k(const float* __restrict__ y,
                                                  float2* __restrict__ H) {
    const int tid = threadIdx.x;
    const int cl = tid & 31;         // cpair lane
    const int sl = tid >> 5;         // 0..7
    const int bs = blockIdx.x & 15;  // s-tile
    const int bc = blockIdx.x >> 4;  // c-tile 0..63
    const int cpg = bc * 32 + cl;    // global cpair
    const int c0 = 2 * cpg;
    const float2 stp = make_float2(0.99518472667219693f, 0.09801714032956060f);

#pragma unroll
    for (int ii = 0; ii < 2; ++ii) {
        const int s = 16 * bs + ii * 8 + sl;
        float2 f[16];
        float sn, cs;
        __sincosf((float)s * TWOPI_16384, &sn, &cs);
        float2 w = make_float2(0.5f * cs, 0.5f * sn);  // 0.5*E(s/16384)
#pragma unroll
        for (int j = 0; j < 16; ++j) {
            const int k = j * 256 + s;
            if (k == 0) {
                float2 r0v = *(const float2*)(y + c0);  // y[0][c0], y[0][c1]
                f[j] = make_float2(0.5f * r0v.x, 0.5f * r0v.y);
            } else {
                float2 A = *(const float2*)(y + (size_t)k * NF + c0);
                float2 Bm = *(const float2*)(y + (size_t)(NF - k) * NF + c0);
                float re = A.x + Bm.y;   // t0[k] + t1[N-k]
                float im = A.y - Bm.x;   // t1[k] - t0[N-k]
                f[j] = make_float2(re * w.x - im * w.y, re * w.y + im * w.x);
            }
            w = cmul(w, stp);  // step E(256/16384)
        }
        fft16(f);  // G_a[s]
        __sincosf((float)s * TWOPI_4096, &sn, &cs);
        const float2 wb = make_float2(cs, sn);
        float2 wa = wb;
#pragma unroll
        for (int a = 1; a < 16; ++a) { f[a] = cmul(f[a], wa); wa = cmul(wa, wb); }
#pragma unroll
        for (int a = 0; a < 16; ++a)
            H[(size_t)(a * 256 + s) * 2048 + cpg] = f[a];
    }
}

// ---- K2b: DFT256 over s per (a, cpair) + unpack + coalesced out writes ----
// block = (a-pair {ap, 15-ap}, 16 cpairs). LDS 64 KiB reused: Q then v.
__global__ __launch_bounds__(256) void colpass2_k(const float2* __restrict__ H,
                                                  const float* __restrict__ y,
                                                  float* __restrict__ out) {
    __shared__ float2 lds[8192];  // 64 KiB
    const int tid = threadIdx.x;
    const int cp = tid & 15;
    const int g = tid >> 4;          // 0..15
    const int ap = blockIdx.x & 7;   // a-pair
    const int bc = blockIdx.x >> 3;  // c-tile 0..127
    const int cpg = bc * 16 + cp;
    const int c0 = 2 * cpg;
    int aabs0 = ap, aabs1 = 15 - ap;

    // phase 1: per (A, s0=g): P_b = FFT16 over s1 of H; Q_b = P_b*E(b g/256)
#pragma unroll
    for (int A = 0; A < 2; ++A) {
        const int abase = (A ? aabs1 : aabs0) * 256;
        float2 f[16];
#pragma unroll
        for (int s1 = 0; s1 < 16; ++s1)
            f[s1] = H[(size_t)(abase + 16 * s1 + g) * 2048 + cpg];
        fft16(f);
        float sn, cs;
        __sincosf((float)g * TWOPI_256, &sn, &cs);
        const float2 wb = make_float2(cs, sn);
        float2 w = wb;
#pragma unroll
        for (int b = 1; b < 16; ++b) { f[b] = cmul(f[b], w); w = cmul(w, wb); }
#pragma unroll
        for (int b = 0; b < 16; ++b)
            lds[((A * 16 + b) * 16 + g) * 16 + cp] = f[b];  // Q[A][b][g][cp]
    }
    __syncthreads();  // Q ready

    // phase 2: b = g: v^{(A)}[b+16c] = FFT16 over s0 of Q[A][b][s0][cp]
    float2 v0[16], v1[16];
    {
        float2 f[16];
#pragma unroll
        for (int s0 = 0; s0 < 16; ++s0) f[s0] = lds[(g * 16 + s0) * 16 + cp];
        fft16(f);
#pragma unroll
        for (int c = 0; c < 16; ++c) v0[c] = f[c];
#pragma unroll
        for (int s0 = 0; s0 < 16; ++s0)
            f[s0] = lds[((16 + g) * 16 + s0) * 16 + cp];
        fft16(f);
#pragma unroll
        for (int c = 0; c < 16; ++c) v1[c] = f[c];
    }
    __syncthreads();  // all Q reads done; LDS reusable

    // stage v: lds_v[A][m = g+16c][cp]
#pragma unroll
    for (int c = 0; c < 16; ++c) {
        lds[(g + 16 * c) * 16 + cp] = v0[c];
        lds[(256 + g + 16 * c) * 16 + cp] = v1[c];
    }
    __syncthreads();

    // write-out (FIXED): n' = na + 16m with m in [0,128) => n' < 2048.
    //   out[2n'][c0,c1]   = v[aout][m]       + (a0h, a1h)
    //   out[2n'+1][c0,c1] = v[1-aout][255-m] + (a0h, a1h)   (= v_{4095-n'})
    float2 h0 = *(const float2*)(y + c0);  // y[0][c0], y[0][c1] (L3-hot)
    const float a0h = 0.5f * h0.x, a1h = 0.5f * h0.y;
    const int aout = g >> 3;  // 0..1
    const int mh = g & 7;     // 0..7
    const int na = aout ? aabs1 : aabs0;
#pragma unroll
    for (int mi = 0; mi < 16; ++mi) {
        const int m = mh * 16 + mi;  // 0..127
        const int n = na + 16 * m;   // < 2048
        float2 vA = lds[(aout * 256 + m) * 16 + cp];
        float2 vB = lds[((1 - aout) * 256 + (255 - m)) * 16 + cp];
        *(float2*)(out + (size_t)(2 * n) * NF + c0) =
            make_float2(vA.x + a0h, vA.y + a1h);
        *(float2*)(out + (size_t)(2 * n + 1) * NF + c0) =
            make_float2(vB.x + a0h, vB.y + a1h);
    }
}

// ---- fallback path kernels (verified r4) ----
__global__ __launch_bounds__(256) void dct_rows_k(const float* __restrict__ yt,
                                                  float* __restrict__ ot) {
    __shared__ float2 buf[4096];
    const int t = threadIdx.x;
    const size_t r0 = (size_t)blockIdx.x * 2;
    const float* t0 = yt + r0 * NF;
    const float* t1 = t0 + NF;
    const float a0h = 0.5f * t0[0];
    const float a1h = 0.5f * t1[0];

    float sn, cs;
    __sincosf((float)t * TWOPI_16384, &sn, &cs);
    float2 w = make_float2(0.5f * cs, 0.5f * sn);
    const float2 stp = make_float2(0.99518472667219693f, 0.09801714032956060f);
    float2 r[16];
#pragma unroll
    for (int i = 0; i < 16; ++i) {
        const int k = t + 256 * i;
        if (k == 0) {
            r[i] = make_float2(a0h, a1h);
        } else {
            float re = t0[k] + t1[NF - k];
            float im = t1[k] - t0[NF - k];
            r[i] = make_float2(re * w.x - im * w.y, re * w.y + im * w.x);
        }
        w = cmul(w, stp);
    }
    fftA_store(r, buf, t);
    fft4096_tail(buf, t);

    float* o0 = ot + r0 * NF;
    float* o1 = o0 + NF;
#pragma unroll
    for (int u = 0; u < 8; ++u) {
        const int n = t + 256 * u;
        float2 vn = buf[n];
        float2 vm = buf[NF - 1 - n];
        ((float2*)o0)[n] = make_float2(vn.x + a0h, vm.x + a0h);
        ((float2*)o1)[n] = make_float2(vn.y + a1h, vm.y + a1h);
    }
}

__global__ __launch_bounds__(256) void transpose_k(const float* __restrict__ in,
                                                   float* __restrict__ out) {
    __shared__ float tile[32][33];
    const int tx = threadIdx.x;  // 0..7
    const int ty = threadIdx.y;  // 0..31
    const int c0 = blockIdx.x * 32;
    const int r0 = blockIdx.y * 32;

    float4 v = *(const float4*)(in + (size_t)(r0 + ty) * NF + c0 + 4 * tx);
    tile[ty][4 * tx + 0] = v.x;
    tile[ty][4 * tx + 1] = v.y;
    tile[ty][4 * tx + 2] = v.z;
    tile[ty][4 * tx + 3] = v.w;
    __syncthreads();

    float4 o;
    o.x = tile[4 * tx + 0][ty];
    o.y = tile[4 * tx + 1][ty];
    o.z = tile[4 * tx + 2][ty];
    o.w = tile[4 * tx + 3][ty];
    *(float4*)(out + (size_t)(c0 + ty) * NF + r0 + 4 * tx) = o;
}

extern "C" void kernel_launch(void* const* d_in, const int* in_sizes, int n_in,
                              void* d_out, int out_size, void* d_ws, size_t ws_size,
                              hipStream_t stream) {
    const float* x = (const float*)d_in[0];
    float* out = (float*)d_out;
    float* y = (float*)d_ws;  // 64 MiB: stage-1 output

    if (ws_size >= ((size_t)128 << 20)) {
        // transpose-free 3-kernel path: H in second 64 MiB of ws
        float2* H = (float2*)(y + ((size_t)64 << 20) / 4);
        dst_rows_k<<<2048, 256, 0, stream>>>(x, y);
        colpass1_k<<<1024, 256, 0, stream>>>(y, H);
        colpass2_k<<<1024, 256, 0, stream>>>(H, y, out);
    } else {
        // verified 4-kernel fallback
        dim3 tgrid(128, 128), tblk(8, 32);
        dst_rows_k<<<2048, 256, 0, stream>>>(x, y);
        transpose_k<<<tgrid, tblk, 0, stream>>>(y, out);
        dct_rows_k<<<tgrid.x * 16, 256, 0, stream>>>(out, y);  // 2048 blocks
        transpose_k<<<tgrid, tblk, 0, stream>>>(y, out);
    }
}

// Round 12
// 179.679 us; speedup vs baseline: 1.0437x; 1.0012x over previous
//
#include <hip/hip_runtime.h>

// IDCST2 via FFTs: out = C0 @ (x @ S1^T), M=N=4096, fp32.
// Stage 1 (rows): y[p][v] = DST3(x[p])[v]  -- verified dst_rows_k (r4).
// Stage 2 (cols): out[:,v] = DCT3(y[:,v]) via Makhoul pack + 4096-pt DFT_+,
//   SPLIT 16x256 over the row index p (k = j*256 + s) so NO transposes:
//   K2a: G_a[s] = FFT16_j W_{j*256+s};  H_a[s] = G_a[s]*E(a s/4096)
//   K2b: v_{a+16m} = DFT256_s H_a[s]  (two FFT16 passes + LDS exchange),
//        unpack n' in [0,2048): rows 2n' from v_{n'}, 2n'+1 from v_{4095-n'}.
// Pipeline: dst_rows(x->y) ; colpass1(y->H) ; colpass2(H->out).
// [r12 single change: drop pass-B read->write barrier in fft4096_tail.
//  Hazard group = threads 16*k1..16*k1+15 (one wave); intra-wave DS ops
//  execute in program order => no block barrier needed. Isolated test of
//  the r5 suspect (b); r9 already exonerated staged loads (a).]
// Fallback: if ws_size < 128 MiB, run the verified 4-kernel path.

#define NF 4096
#define TWOPI_16384 3.8349519697141029e-4f  // 2*pi/16384
#define TWOPI_4096  1.5339807878856412e-3f  // 2*pi/4096
#define TWOPI_256   2.4543692606170259e-2f  // 2*pi/256

__device__ __forceinline__ float2 cmul(float2 a, float2 b) {
    return make_float2(a.x * b.x - a.y * b.y, a.x * b.y + a.y * b.x);
}
__device__ __forceinline__ float2 cadd(float2 a, float2 b) {
    return make_float2(a.x + b.x, a.y + b.y);
}
__device__ __forceinline__ float2 csub(float2 a, float2 b) {
    return make_float2(a.x - b.x, a.y - b.y);
}
__device__ __forceinline__ float2 muli(float2 a) {  // +i * a (positive-sign DFT)
    return make_float2(-a.y, a.x);
}

// 16-point DFT_+ in registers, natural order in/out (verified r2/r3).
__device__ __forceinline__ void fft16(float2 f[16]) {
    float2 s[16];
#pragma unroll
    for (int b = 0; b < 4; ++b) {
        float2 x0 = f[b], x1 = f[b + 4], x2 = f[b + 8], x3 = f[b + 12];
        float2 t0 = cadd(x0, x2), t1 = csub(x0, x2);
        float2 t2 = cadd(x1, x3), t3 = csub(x1, x3);
        s[b]      = cadd(t0, t2);
        s[4 + b]  = cadd(t1, muli(t3));
        s[8 + b]  = csub(t0, t2);
        s[12 + b] = csub(t1, muli(t3));
    }
    const float2 w1 = make_float2(0.92387953251128674f, 0.38268343236508977f);
    const float2 w2 = make_float2(0.70710678118654752f, 0.70710678118654752f);
    const float2 w3 = make_float2(0.38268343236508977f, 0.92387953251128674f);
    const float2 w6 = make_float2(-0.70710678118654752f, 0.70710678118654752f);
    const float2 w9 = make_float2(-0.92387953251128674f, -0.38268343236508977f);
    s[5]  = cmul(s[5], w1);
    s[6]  = cmul(s[6], w2);
    s[7]  = cmul(s[7], w3);
    s[9]  = cmul(s[9], w2);
    s[10] = muli(s[10]);
    s[11] = cmul(s[11], w6);
    s[13] = cmul(s[13], w3);
    s[14] = cmul(s[14], w6);
    s[15] = cmul(s[15], w9);
#pragma unroll
    for (int al = 0; al < 4; ++al) {
        float2 x0 = s[4 * al + 0], x1 = s[4 * al + 1];
        float2 x2 = s[4 * al + 2], x3 = s[4 * al + 3];
        float2 t0 = cadd(x0, x2), t1 = csub(x0, x2);
        float2 t2 = cadd(x1, x3), t3 = csub(x1, x3);
        f[al]      = cadd(t0, t2);
        f[4 + al]  = cadd(t1, muli(t3));
        f[8 + al]  = csub(t0, t2);
        f[12 + al] = csub(t1, muli(t3));
    }
}

// Pass A tail: r[] holds W_{i*256+t}; fft16, twiddle E(t*k1/4096), store.
__device__ __forceinline__ void fftA_store(float2 r[16], float2* __restrict__ buf,
                                           const int t) {
    fft16(r);
    float sn, cs;
    __sincosf((float)t * TWOPI_4096, &sn, &cs);
    const float2 wb = make_float2(cs, sn);
    float2 w = wb;
#pragma unroll
    for (int k1 = 1; k1 < 16; ++k1) { r[k1] = cmul(r[k1], w); w = cmul(w, wb); }
#pragma unroll
    for (int i = 0; i < 16; ++i) buf[i * 256 + t] = r[i];
}

// Passes B and C (A-output already in buf). Leaves X natural order.
// Pass B read->write needs NO barrier: row k1 is touched only by threads
// 16*k1..16*k1+15 (one wave); intra-wave DS ops execute in order.
__device__ __forceinline__ void fft4096_tail(float2* __restrict__ buf, const int t) {
    float2 r[16];
    __syncthreads();  // (1) A writes -> B reads (cross-wave)
    {
        const int k1 = t >> 4, m2 = t & 15;
        const int base = k1 * 256 + m2;
#pragma unroll
        for (int i = 0; i < 16; ++i) r[i] = buf[base + i * 16];
        fft16(r);
        float sn, cs;
        __sincosf((float)m2 * TWOPI_256, &sn, &cs);
        const float2 wb = make_float2(cs, sn);
        float2 w = wb;
#pragma unroll
        for (int j1 = 1; j1 < 16; ++j1) { r[j1] = cmul(r[j1], w); w = cmul(w, wb); }
        const int bw = k1 * 256 + (m2 ^ k1);  // swizzled write, intra-wave safe
#pragma unroll
        for (int j1 = 0; j1 < 16; ++j1) buf[bw + j1 * 16] = r[j1];
    }
    __syncthreads();  // (2) B writes -> C reads (cross-wave)
    {
        const int k1 = t & 15;
        const int bc = k1 * 256 + (t >> 4) * 16;
#pragma unroll
        for (int i = 0; i < 16; ++i) r[i] = buf[bc + (i ^ k1)];
        fft16(r);
        __syncthreads();  // (3) C reads -> natural-order writes (cross-wave)
#pragma unroll
        for (int j2 = 0; j2 < 16; ++j2) buf[j2 * 256 + t] = r[j2];
    }
    __syncthreads();  // (4) C writes -> unpack reads
}

// ---- stage 1: DST-III along rows; two rows per block (verified r4) ----
__global__ __launch_bounds__(256) void dst_rows_k(const float* __restrict__ x,
                                                  float* __restrict__ y) {
    __shared__ float2 buf[4096];  // 32 KiB
    const int t = threadIdx.x;
    const size_t r0 = (size_t)blockIdx.x * 2;
    const float* x0 = x + r0 * NF;
    const float* x1 = x0 + NF;

    float sn, cs;
    __sincosf((float)t * TWOPI_16384, &sn, &cs);
    float2 w = make_float2(0.5f * cs, 0.5f * sn);  // 1/2 folded in
    const float2 stp = make_float2(0.99518472667219693f, 0.09801714032956060f);
    float2 r[16];
#pragma unroll
    for (int i = 0; i < 16; ++i) {
        const int k = t + 256 * i;
        float2 ww = make_float2(0.f, 0.f);
        if (k > 0) {
            float re = x0[NF - k] + x1[k];
            float im = x1[NF - k] - x0[k];
            ww = make_float2(re * w.x - im * w.y, re * w.y + im * w.x);
        }
        r[i] = ww;
        w = cmul(w, stp);
    }
    fftA_store(r, buf, t);
    fft4096_tail(buf, t);

    float* y0 = y + r0 * NF;
    float* y1 = y0 + NF;
#pragma unroll
    for (int u = 0; u < 8; ++u) {
        const int n = t + 256 * u;
        float2 vn = buf[n];
        float2 vm = buf[NF - 1 - n];
        ((float2*)y0)[n] = make_float2(vn.x, -vm.x);
        ((float2*)y1)[n] = make_float2(vn.y, -vm.y);
    }
}

// ---- K2a: column pack + FFT16 over j + twiddle -> H  (no LDS) ----
// H[a*256+s][cpair] = E(a s/4096) * sum_j W_{j*256+s} E(a j/16)
__global__ __launch_bounds__(256) void colpass1_k(const float* __restrict__ y,
                                                  float2* __restrict__ H) {
    const int tid = threadIdx.x;
    const int cl = tid & 31;         // cpair lane
    const int sl = tid >> 5;         // 0..7
    const int bs = blockIdx.x & 15;  // s-tile
    const int bc = blockIdx.x >> 4;  // c-tile 0..63
    const int cpg = bc * 32 + cl;    // global cpair
    const int c0 = 2 * cpg;
    const float2 stp = make_float2(0.99518472667219693f, 0.09801714032956060f);

#pragma unroll
    for (int ii = 0; ii < 2; ++ii) {
        const int s = 16 * bs + ii * 8 + sl;
        float2 f[16];
        float sn, cs;
        __sincosf((float)s * TWOPI_16384, &sn, &cs);
        float2 w = make_float2(0.5f * cs, 0.5f * sn);  // 0.5*E(s/16384)
#pragma unroll
        for (int j = 0; j < 16; ++j) {
            const int k = j * 256 + s;
            if (k == 0) {
                float2 r0v = *(const float2*)(y + c0);  // y[0][c0], y[0][c1]
                f[j] = make_float2(0.5f * r0v.x, 0.5f * r0v.y);
            } else {
                float2 A = *(const float2*)(y + (size_t)k * NF + c0);
                float2 Bm = *(const float2*)(y + (size_t)(NF - k) * NF + c0);
                float re = A.x + Bm.y;   // t0[k] + t1[N-k]
                float im = A.y - Bm.x;   // t1[k] - t0[N-k]
                f[j] = make_float2(re * w.x - im * w.y, re * w.y + im * w.x);
            }
            w = cmul(w, stp);  // step E(256/16384)
        }
        fft16(f);  // G_a[s]
        __sincosf((float)s * TWOPI_4096, &sn, &cs);
        const float2 wb = make_float2(cs, sn);
        float2 wa = wb;
#pragma unroll
        for (int a = 1; a < 16; ++a) { f[a] = cmul(f[a], wa); wa = cmul(wa, wb); }
#pragma unroll
        for (int a = 0; a < 16; ++a)
            H[(size_t)(a * 256 + s) * 2048 + cpg] = f[a];
    }
}

// ---- K2b: DFT256 over s per (a, cpair) + unpack + coalesced out writes ----
// block = (a-pair {ap, 15-ap}, 16 cpairs). LDS 64 KiB reused: Q then v.
__global__ __launch_bounds__(256) void colpass2_k(const float2* __restrict__ H,
                                                  const float* __restrict__ y,
                                                  float* __restrict__ out) {
    __shared__ float2 lds[8192];  // 64 KiB
    const int tid = threadIdx.x;
    const int cp = tid & 15;
    const int g = tid >> 4;          // 0..15
    const int ap = blockIdx.x & 7;   // a-pair
    const int bc = blockIdx.x >> 3;  // c-tile 0..127
    const int cpg = bc * 16 + cp;
    const int c0 = 2 * cpg;
    int aabs0 = ap, aabs1 = 15 - ap;

    // phase 1: per (A, s0=g): P_b = FFT16 over s1 of H; Q_b = P_b*E(b g/256)
#pragma unroll
    for (int A = 0; A < 2; ++A) {
        const int abase = (A ? aabs1 : aabs0) * 256;
        float2 f[16];
#pragma unroll
        for (int s1 = 0; s1 < 16; ++s1)
            f[s1] = H[(size_t)(abase + 16 * s1 + g) * 2048 + cpg];
        fft16(f);
        float sn, cs;
        __sincosf((float)g * TWOPI_256, &sn, &cs);
        const float2 wb = make_float2(cs, sn);
        float2 w = wb;
#pragma unroll
        for (int b = 1; b < 16; ++b) { f[b] = cmul(f[b], w); w = cmul(w, wb); }
#pragma unroll
        for (int b = 0; b < 16; ++b)
            lds[((A * 16 + b) * 16 + g) * 16 + cp] = f[b];  // Q[A][b][g][cp]
    }
    __syncthreads();  // Q ready

    // phase 2: b = g: v^{(A)}[b+16c] = FFT16 over s0 of Q[A][b][s0][cp]
    float2 v0[16], v1[16];
    {
        float2 f[16];
#pragma unroll
        for (int s0 = 0; s0 < 16; ++s0) f[s0] = lds[(g * 16 + s0) * 16 + cp];
        fft16(f);
#pragma unroll
        for (int c = 0; c < 16; ++c) v0[c] = f[c];
#pragma unroll
        for (int s0 = 0; s0 < 16; ++s0)
            f[s0] = lds[((16 + g) * 16 + s0) * 16 + cp];
        fft16(f);
#pragma unroll
        for (int c = 0; c < 16; ++c) v1[c] = f[c];
    }
    __syncthreads();  // all Q reads done; LDS reusable

    // stage v: lds_v[A][m = g+16c][cp]
#pragma unroll
    for (int c = 0; c < 16; ++c) {
        lds[(g + 16 * c) * 16 + cp] = v0[c];
        lds[(256 + g + 16 * c) * 16 + cp] = v1[c];
    }
    __syncthreads();

    // write-out: n' = na + 16m with m in [0,128) => n' < 2048.
    //   out[2n'][c0,c1]   = v[aout][m]       + (a0h, a1h)
    //   out[2n'+1][c0,c1] = v[1-aout][255-m] + (a0h, a1h)   (= v_{4095-n'})
    float2 h0 = *(const float2*)(y + c0);  // y[0][c0], y[0][c1] (L3-hot)
    const float a0h = 0.5f * h0.x, a1h = 0.5f * h0.y;
    const int aout = g >> 3;  // 0..1
    const int mh = g & 7;     // 0..7
    const int na = aout ? aabs1 : aabs0;
#pragma unroll
    for (int mi = 0; mi < 16; ++mi) {
        const int m = mh * 16 + mi;  // 0..127
        const int n = na + 16 * m;   // < 2048
        float2 vA = lds[(aout * 256 + m) * 16 + cp];
        float2 vB = lds[((1 - aout) * 256 + (255 - m)) * 16 + cp];
        *(float2*)(out + (size_t)(2 * n) * NF + c0) =
            make_float2(vA.x + a0h, vA.y + a1h);
        *(float2*)(out + (size_t)(2 * n + 1) * NF + c0) =
            make_float2(vB.x + a0h, vB.y + a1h);
    }
}

// ---- fallback path kernels (verified r4) ----
__global__ __launch_bounds__(256) void dct_rows_k(const float* __restrict__ yt,
                                                  float* __restrict__ ot) {
    __shared__ float2 buf[4096];
    const int t = threadIdx.x;
    const size_t r0 = (size_t)blockIdx.x * 2;
    const float* t0 = yt + r0 * NF;
    const float* t1 = t0 + NF;
    const float a0h = 0.5f * t0[0];
    const float a1h = 0.5f * t1[0];

    float sn, cs;
    __sincosf((float)t * TWOPI_16384, &sn, &cs);
    float2 w = make_float2(0.5f * cs, 0.5f * sn);
    const float2 stp = make_float2(0.99518472667219693f, 0.09801714032956060f);
    float2 r[16];
#pragma unroll
    for (int i = 0; i < 16; ++i) {
        const int k = t + 256 * i;
        if (k == 0) {
            r[i] = make_float2(a0h, a1h);
        } else {
            float re = t0[k] + t1[NF - k];
            float im = t1[k] - t0[NF - k];
            r[i] = make_float2(re * w.x - im * w.y, re * w.y + im * w.x);
        }
        w = cmul(w, stp);
    }
    fftA_store(r, buf, t);
    fft4096_tail(buf, t);

    float* o0 = ot + r0 * NF;
    float* o1 = o0 + NF;
#pragma unroll
    for (int u = 0; u < 8; ++u) {
        const int n = t + 256 * u;
        float2 vn = buf[n];
        float2 vm = buf[NF - 1 - n];
        ((float2*)o0)[n] = make_float2(vn.x + a0h, vm.x + a0h);
        ((float2*)o1)[n] = make_float2(vn.y + a1h, vm.y + a1h);
    }
}

__global__ __launch_bounds__(256) void transpose_k(const float* __restrict__ in,
                                                   float* __restrict__ out) {
    __shared__ float tile[32][33];
    const int tx = threadIdx.x;  // 0..7
    const int ty = threadIdx.y;  // 0..31
    const int c0 = blockIdx.x * 32;
    const int r0 = blockIdx.y * 32;

    float4 v = *(const float4*)(in + (size_t)(r0 + ty) * NF + c0 + 4 * tx);
    tile[ty][4 * tx + 0] = v.x;
    tile[ty][4 * tx + 1] = v.y;
    tile[ty][4 * tx + 2] = v.z;
    tile[ty][4 * tx + 3] = v.w;
    __syncthreads();

    float4 o;
    o.x = tile[4 * tx + 0][ty];
    o.y = tile[4 * tx + 1][ty];
    o.z = tile[4 * tx + 2][ty];
    o.w = tile[4 * tx + 3][ty];
    *(float4*)(out + (size_t)(c0 + ty) * NF + r0 + 4 * tx) = o;
}

extern "C" void kernel_launch(void* const* d_in, const int* in_sizes, int n_in,
                              void* d_out, int out_size, void* d_ws, size_t ws_size,
                              hipStream_t stream) {
    const float* x = (const float*)d_in[0];
    float* out = (float*)d_out;
    float* y = (float*)d_ws;  // 64 MiB: stage-1 output

    if (ws_size >= ((size_t)128 << 20)) {
        // transpose-free 3-kernel path: H in second 64 MiB of ws
        float2* H = (float2*)(y + ((size_t)64 << 20) / 4);
        dst_rows_k<<<2048, 256, 0, stream>>>(x, y);
        colpass1_k<<<1024, 256, 0, stream>>>(y, H);
        colpass2_k<<<1024, 256, 0, stream>>>(H, y, out);
    } else {
        // verified 4-kernel fallback
        dim3 tgrid(128, 128), tblk(8, 32);
        dst_rows_k<<<2048, 256, 0, stream>>>(x, y);
        transpose_k<<<tgrid, tblk, 0, stream>>>(y, out);
        dct_rows_k<<<2048, 256, 0, stream>>>(out, y);
        transpose_k<<<tgrid, tblk, 0, stream>>>(y, out);
    }
}